// Round 6
// baseline (445.649 us; speedup 1.0000x reference)
//
#include <hip/hip_runtime.h>
#include <math.h>

#define NBS 1600      // B*S
#define LL 20
#define EE 300
#define NH 16
#define VD 16
#define HID 256
#define QD 200

typedef short bf16x8 __attribute__((ext_vector_type(8)));
typedef float f32x4 __attribute__((ext_vector_type(4)));

__device__ __forceinline__ short f2b(float f) {
    union { float f; unsigned u; } c; c.f = f;
    unsigned r = (c.u + 0x7FFFu + ((c.u >> 16) & 1u)) >> 16;  // RNE
    return (short)r;
}

__device__ __forceinline__ float ftanh(float a) {
    a = fminf(fmaxf(a, -15.f), 15.f);
    float t = __expf(2.f * a);
    return (t - 1.f) / (t + 1.f);
}

// ===========================================================================
// NEW PATH (needs ~40.4 MB ws)
// ===========================================================================

// news/emb -> Xb bf16 [32000][320]; col300 = 1.0 (bias channel), 301..319 = 0
__global__ void build_xb(const int* __restrict__ news, const float* __restrict__ emb,
                         short* __restrict__ Xb) {
    int idx = blockIdx.x * 256 + threadIdx.x;     // one per 4 elems
    if (idx >= 32000 * 80) return;
    int i = idx / 80, e4 = (idx % 80) * 4;
    short4 o;
    if (e4 < 300) {
        const float4 v = *reinterpret_cast<const float4*>(emb + (size_t)news[i] * EE + e4);
        o.x = f2b(v.x); o.y = f2b(v.y); o.z = f2b(v.z); o.w = f2b(v.w);
    } else if (e4 == 300) {
        o.x = (short)0x3F80; o.y = 0; o.z = 0; o.w = 0;
    } else {
        o.x = o.y = o.z = o.w = 0;
    }
    *reinterpret_cast<short4*>(Xb + (size_t)i * 320 + e4) = o;
}

// Wq [n][e][f] -> WqT bf16 [n][f(320)][e(320)], col300 = qB, zero rows f>=300
__global__ __launch_bounds__(1024) void build_wqt(
    const float* __restrict__ qW, const float* __restrict__ qB, short* __restrict__ WqT)
{
    __shared__ float t[32][33];
    const int n = blockIdx.z;
    const int e0 = blockIdx.x * 32, f0 = blockIdx.y * 32;
    const int tx = threadIdx.x, ty = threadIdx.y;
    const int e = e0 + ty, f = f0 + tx;
    t[ty][tx] = (e < EE && f < EE) ? qW[((size_t)n * EE + e) * EE + f] : 0.f;
    __syncthreads();
    const int fo = f0 + ty, eo = e0 + tx;
    float val;
    if (fo >= EE)      val = 0.f;
    else if (eo < EE)  val = t[tx][ty];
    else if (eo == EE) val = qB[n * EE + fo];
    else               val = 0.f;
    WqT[((size_t)n * 320 + fo) * 320 + eo] = f2b(val);
}

// Wv [n][e][v] -> WvT bf16 [256][320] rows c=n*16+vd, col300 = vB
__global__ void build_wvt(const float* __restrict__ vW, const float* __restrict__ vB,
                          short* __restrict__ WvT) {
    int idx = blockIdx.x * 256 + threadIdx.x;
    if (idx >= 256 * 320) return;
    int c = idx / 320, e = idx % 320;
    int n = c >> 4, vd = c & 15;
    float val = (e < EE) ? vW[((size_t)n * EE + e) * VD + vd]
                         : (e == EE ? vB[n * VD + vd] : 0.f);
    WvT[idx] = f2b(val);
}

// keyW [200][256] fp32 -> bf16 [208][256] (rows >=200 zero)
__global__ void conv_kw(const float* __restrict__ keyW, short* __restrict__ kwb) {
    int idx = blockIdx.x * 256 + threadIdx.x;
    if (idx >= 208 * 256) return;
    int d = idx >> 8;
    kwb[idx] = (d < QD) ? f2b(keyW[idx]) : (short)0;
}

// xv = Xb * WvT^T : [32000][256] bf16.  128x128 tile, 4 waves.
__global__ __launch_bounds__(256) void gemm_xv(
    const short* __restrict__ Xb, const short* __restrict__ WvT, short* __restrict__ xv)
{
    const int nt0 = blockIdx.x * 128;
    const size_t mt0 = (size_t)blockIdx.y * 128;
    const int tid = threadIdx.x, wave = tid >> 6, lane = tid & 63;
    const int lr = lane & 15, lg = lane >> 4;
    const int wm = wave & 1, wn = wave >> 1;

    __shared__ short As[128][68];   // 34 dwords/row: b128 windows tile banks evenly
    __shared__ short Bs[128][68];
    f32x4 acc[4][4] = {};

    for (int ks = 0; ks < 5; ++ks) {
        __syncthreads();
        for (int u = 0; u < 4; ++u) {
            int idx = u * 256 + tid;          // 0..1023
            int rr = idx >> 3, c8 = idx & 7;
            *reinterpret_cast<bf16x8*>(&As[rr][c8 * 8]) =
                *reinterpret_cast<const bf16x8*>(Xb + (mt0 + rr) * 320 + ks * 64 + c8 * 8);
            *reinterpret_cast<bf16x8*>(&Bs[rr][c8 * 8]) =
                *reinterpret_cast<const bf16x8*>(WvT + (size_t)(nt0 + rr) * 320 + ks * 64 + c8 * 8);
        }
        __syncthreads();
        #pragma unroll
        for (int kk = 0; kk < 2; ++kk) {
            bf16x8 af[4], bfv[4];
            #pragma unroll
            for (int f = 0; f < 4; ++f)
                af[f] = *reinterpret_cast<const bf16x8*>(&As[wm * 64 + f * 16 + lr][kk * 32 + lg * 8]);
            #pragma unroll
            for (int f = 0; f < 4; ++f)
                bfv[f] = *reinterpret_cast<const bf16x8*>(&Bs[wn * 64 + f * 16 + lr][kk * 32 + lg * 8]);
            #pragma unroll
            for (int i = 0; i < 4; ++i)
                #pragma unroll
                for (int j = 0; j < 4; ++j)
                    acc[i][j] = __builtin_amdgcn_mfma_f32_16x16x32_bf16(af[i], bfv[j], acc[i][j], 0, 0, 0);
        }
    }
    #pragma unroll
    for (int i = 0; i < 4; ++i)
        #pragma unroll
        for (int j = 0; j < 4; ++j)
            #pragma unroll
            for (int r = 0; r < 4; ++r)
                xv[(mt0 + wm * 64 + i * 16 + lg * 4 + r) * 256 + nt0 + wn * 64 + j * 16 + lr]
                    = f2b(acc[i][j][r]);
}

// ---------------------------------------------------------------------------
// qattn v3: one block per (group of 2 bs, head). 512 threads (8 waves).
// Changes vs v2: stride 328 (164 dw == 4 mod 32 -> conflict-free b128),
// 2-deep B register pipeline, tail distributed (scores+softmax waves 0-3,
// v waves 4-7 with xv prefetched at block start).
// ---------------------------------------------------------------------------
__global__ __launch_bounds__(512, 4) void qattn(
    const short* __restrict__ Xb,    // [32000][320]
    const short* __restrict__ WqT,   // [16][320][320]
    const short* __restrict__ xv,    // [32000][256]
    float*       __restrict__ out1)  // [32000][256]
{
    const int g = blockIdx.x;        // group of 2 bs
    const int n = blockIdx.y;        // head
    const int tid = threadIdx.x, wave = tid >> 6, lane = tid & 63;
    const int lr = lane & 15, lg = lane >> 4;
    const size_t row0 = (size_t)g * 40;

    __shared__ short xs[48][328];    // rows 40..47 zero; stride 164dw == 4 mod 32
    __shared__ short qs[40][328];
    __shared__ short atw[2][32][34]; // per-bs attn (pads zero)

    // zero atw + xs pad rows
    for (int i = tid; i < 1088; i += 512) reinterpret_cast<int*>(atw)[i] = 0;
    for (int i = tid; i < 1312; i += 512) reinterpret_cast<int*>(&xs[40][0])[i] = 0;

    // prefetch xv B-frag for v-phase (waves 4-7) — used ~whole kernel later
    bf16x8 bv;
    if (wave >= 4) {
        const int b = (wave - 4) >> 1;
        #pragma unroll
        for (int j = 0; j < 8; ++j) {
            int m = lg * 8 + j; if (m > 19) m = 19;   // attn cols >=20 are zero
            bv[j] = xv[(row0 + b * 20 + m) * 256 + n * 16 + lr];
        }
    }

    // load xs: 40 rows x 320 cols
    for (int idx = tid; idx < 1600; idx += 512) {
        int l = idx / 40, c8 = idx % 40;
        *reinterpret_cast<bf16x8*>(&xs[l][c8 * 8]) =
            *reinterpret_cast<const bf16x8*>(Xb + (row0 + l) * 320 + c8 * 8);
    }

    const short* wh = WqT + (size_t)n * 320 * 320;
    const bool has2 = (wave >= 4);
    const int ntA = wave * 16 + lr;
    const int ntB = (8 + wave) * 16 + lr;
    const int ntC = has2 ? (16 + (wave - 4)) * 16 + lr : lr;

    // B pipeline: 2-deep register prefetch (issued before the barrier)
    bf16x8 bcur[3], bnx1[3], bnx2[3], acur[3], anxt[3];
    bcur[0] = *reinterpret_cast<const bf16x8*>(wh + (size_t)ntA * 320 + lg * 8);
    bcur[1] = *reinterpret_cast<const bf16x8*>(wh + (size_t)ntB * 320 + lg * 8);
    bcur[2] = *reinterpret_cast<const bf16x8*>(wh + (size_t)ntC * 320 + lg * 8);
    bnx1[0] = *reinterpret_cast<const bf16x8*>(wh + (size_t)ntA * 320 + 32 + lg * 8);
    bnx1[1] = *reinterpret_cast<const bf16x8*>(wh + (size_t)ntB * 320 + 32 + lg * 8);
    bnx1[2] = *reinterpret_cast<const bf16x8*>(wh + (size_t)ntC * 320 + 32 + lg * 8);

    __syncthreads();

    acur[0] = *reinterpret_cast<const bf16x8*>(&xs[lr][lg * 8]);
    acur[1] = *reinterpret_cast<const bf16x8*>(&xs[16 + lr][lg * 8]);
    acur[2] = *reinterpret_cast<const bf16x8*>(&xs[32 + lr][lg * 8]);

    f32x4 acc[3][3] = {};
    #pragma unroll
    for (int ks = 0; ks < 10; ++ks) {
        if (ks < 8) {
            const int kc = (ks + 2) * 32 + lg * 8;
            bnx2[0] = *reinterpret_cast<const bf16x8*>(wh + (size_t)ntA * 320 + kc);
            bnx2[1] = *reinterpret_cast<const bf16x8*>(wh + (size_t)ntB * 320 + kc);
            bnx2[2] = *reinterpret_cast<const bf16x8*>(wh + (size_t)ntC * 320 + kc);
        }
        if (ks < 9) {
            const int kc = (ks + 1) * 32 + lg * 8;
            anxt[0] = *reinterpret_cast<const bf16x8*>(&xs[lr][kc]);
            anxt[1] = *reinterpret_cast<const bf16x8*>(&xs[16 + lr][kc]);
            anxt[2] = *reinterpret_cast<const bf16x8*>(&xs[32 + lr][kc]);
        }
        #pragma unroll
        for (int mt = 0; mt < 3; ++mt) {
            acc[mt][0] = __builtin_amdgcn_mfma_f32_16x16x32_bf16(acur[mt], bcur[0], acc[mt][0], 0, 0, 0);
            acc[mt][1] = __builtin_amdgcn_mfma_f32_16x16x32_bf16(acur[mt], bcur[1], acc[mt][1], 0, 0, 0);
        }
        if (has2) {
            #pragma unroll
            for (int mt = 0; mt < 3; ++mt)
                acc[mt][2] = __builtin_amdgcn_mfma_f32_16x16x32_bf16(acur[mt], bcur[2], acc[mt][2], 0, 0, 0);
        }
        #pragma unroll
        for (int t = 0; t < 3; ++t) { bcur[t] = bnx1[t]; bnx1[t] = bnx2[t]; acur[t] = anxt[t]; }
    }

    // write q tile (rows < 40)
    #pragma unroll
    for (int ti = 0; ti < 3; ++ti) {
        if (ti < 2 || has2) {
            const int col = ((ti < 2) ? (ti * 8 + wave) * 16 : (16 + (wave - 4)) * 16) + lr;
            #pragma unroll
            for (int mt = 0; mt < 3; ++mt)
                #pragma unroll
                for (int r = 0; r < 4; ++r) {
                    const int row = mt * 16 + lg * 4 + r;
                    if (row < 40) qs[row][col] = f2b(acc[mt][ti][r]);
                }
        }
    }
    __syncthreads();

    // ---- scores + in-register softmax: waves 0-3, one (bs, mt-tile) each ----
    if (wave < 4) {
        const int b = wave >> 1;
        const int mts = wave & 1;
        int rA = b * 20 + mts * 16 + lr; if (rA > 39) rA = 39;   // q rows
        const int rB0 = b * 20 + lr;                             // x rows, nts=0
        int rB1 = b * 20 + 16 + lr; if (rB1 > 47) rB1 = 47;      // x rows, nts=1

        f32x4 sE0 = {}, sO0 = {}, sE1 = {}, sO1 = {};
        #pragma unroll
        for (int ks = 0; ks < 10; ks += 2) {
            const int k0 = ks * 32 + lg * 8, k1 = (ks + 1) * 32 + lg * 8;
            bf16x8 aE  = *reinterpret_cast<const bf16x8*>(&qs[rA][k0]);
            bf16x8 aO  = *reinterpret_cast<const bf16x8*>(&qs[rA][k1]);
            bf16x8 b0E = *reinterpret_cast<const bf16x8*>(&xs[rB0][k0]);
            bf16x8 b0O = *reinterpret_cast<const bf16x8*>(&xs[rB0][k1]);
            bf16x8 b1E = *reinterpret_cast<const bf16x8*>(&xs[rB1][k0]);
            bf16x8 b1O = *reinterpret_cast<const bf16x8*>(&xs[rB1][k1]);
            sE0 = __builtin_amdgcn_mfma_f32_16x16x32_bf16(aE, b0E, sE0, 0, 0, 0);
            sO0 = __builtin_amdgcn_mfma_f32_16x16x32_bf16(aO, b0O, sO0, 0, 0, 0);
            sE1 = __builtin_amdgcn_mfma_f32_16x16x32_bf16(aE, b1E, sE1, 0, 0, 0);
            sO1 = __builtin_amdgcn_mfma_f32_16x16x32_bf16(aO, b1O, sO1, 0, 0, 0);
        }
        f32x4 s0 = sE0 + sO0;
        f32x4 s1 = sE1 + sO1;

        const float scl = 0.057735026918962584f;  // 1/sqrt(300)
        #pragma unroll
        for (int r = 0; r < 4; ++r) {
            float v0 = s0[r] * scl;
            float v1 = s1[r] * scl;
            float mx = (lr < 4) ? fmaxf(v0, v1) : v0;
            mx = fmaxf(mx, __shfl_xor(mx, 1));
            mx = fmaxf(mx, __shfl_xor(mx, 2));
            mx = fmaxf(mx, __shfl_xor(mx, 4));
            mx = fmaxf(mx, __shfl_xor(mx, 8));
            float e0 = __expf(v0 - mx);
            float e1 = (lr < 4) ? __expf(v1 - mx) : 0.f;
            float sm = e0 + e1;
            sm += __shfl_xor(sm, 1);
            sm += __shfl_xor(sm, 2);
            sm += __shfl_xor(sm, 4);
            sm += __shfl_xor(sm, 8);
            const float inv = 1.f / sm;
            const int row = mts * 16 + lg * 4 + r;
            if (row < LL) {
                atw[b][row][lr]      = f2b(e0 * inv);
                atw[b][row][16 + lr] = f2b(e1 * inv);   // lr>=4 writes 0
            }
        }
    }
    __syncthreads();

    // ---- v = attn * xv : waves 4-7, one (bs, mt-tile) each ----
    if (wave >= 4) {
        const int b = (wave - 4) >> 1;
        const int mtv = (wave - 4) & 1;
        bf16x8 va = *reinterpret_cast<const bf16x8*>(&atw[b][mtv * 16 + lr][lg * 8]);
        f32x4 z = {0.f, 0.f, 0.f, 0.f};
        f32x4 vo = __builtin_amdgcn_mfma_f32_16x16x32_bf16(va, bv, z, 0, 0, 0);
        #pragma unroll
        for (int r = 0; r < 4; ++r) {
            const int rowl = mtv * 16 + lg * 4 + r;
            if (rowl < LL)
                out1[(row0 + b * 20 + rowl) * 256 + n * 16 + lr] = vo[r];
        }
    }
}

// ---------------------------------------------------------------------------
// Additive attention pooling per bs, MFMA add_key. grid 1600, block 256.
// ---------------------------------------------------------------------------
__global__ __launch_bounds__(256) void nrms_pool_mfma(
    const float* __restrict__ out1,
    const short* __restrict__ kwb,    // [208][256] bf16
    const float* __restrict__ keyB,   // [200]
    const float* __restrict__ query,  // [200]
    float*       __restrict__ out2)   // [NBS][256]
{
    const int bs   = blockIdx.x;
    const int tid  = threadIdx.x;
    const int wave = tid >> 6;
    const int lane = tid & 63;
    const int lr   = lane & 15;
    const int lg   = lane >> 4;

    __shared__ float mh[LL][257];
    __shared__ short mhb[32][264];   // 132 dw == 4 mod 32
    __shared__ float s2p[32];

    for (int i = tid; i < 12 * 128; i += 256) {
        const int r = 20 + i / 128, c = (i % 128) * 2;
        *reinterpret_cast<int*>(&mhb[r][c]) = 0;
    }
    if (tid < 32) s2p[tid] = 0.f;

    for (int idx = tid; idx < LL * 64; idx += 256) {
        const int l = idx >> 6, h4 = (idx & 63) * 4;
        const float4 v = *reinterpret_cast<const float4*>(out1 + ((size_t)bs * LL + l) * HID + h4);
        mh[l][h4] = v.x; mh[l][h4 + 1] = v.y; mh[l][h4 + 2] = v.z; mh[l][h4 + 3] = v.w;
        mhb[l][h4] = f2b(v.x); mhb[l][h4 + 1] = f2b(v.y);
        mhb[l][h4 + 2] = f2b(v.z); mhb[l][h4 + 3] = f2b(v.w);
    }
    __syncthreads();

    for (int t = wave; t < 26; t += 4) {
        const int mt = t & 1, nt = t >> 1;
        f32x4 acc = {0.f, 0.f, 0.f, 0.f};
        const short* ap = &mhb[mt * 16 + lr][lg * 8];
        const short* bp = kwb + (nt * 16 + lr) * 256 + lg * 8;
        #pragma unroll
        for (int k = 0; k < 8; ++k) {
            bf16x8 a = *reinterpret_cast<const bf16x8*>(ap + k * 32);
            bf16x8 b = *reinterpret_cast<const bf16x8*>(bp + k * 32);
            acc = __builtin_amdgcn_mfma_f32_16x16x32_bf16(a, b, acc, 0, 0, 0);
        }
        const int d = nt * 16 + lr;
        const float qd = (d < QD) ? query[d] : 0.f;
        const float kb = (d < QD) ? keyB[d] : 0.f;
        float vals[4];
        #pragma unroll
        for (int r = 0; r < 4; ++r) vals[r] = qd * ftanh(acc[r] + kb);
        #pragma unroll
        for (int off = 1; off < 16; off <<= 1) {
            #pragma unroll
            for (int r = 0; r < 4; ++r) vals[r] += __shfl_xor(vals[r], off);
        }
        if (lr == 0) {
            #pragma unroll
            for (int r = 0; r < 4; ++r)
                atomicAdd(&s2p[mt * 16 + lg * 4 + r], vals[r]);
        }
    }
    __syncthreads();

    if (tid == 0) {
        float mx = -1e30f;
        #pragma unroll
        for (int l = 0; l < LL; ++l) mx = fmaxf(mx, s2p[l] * 0.07071067811865475f);
        float sum = 0.f;
        float e[LL];
        #pragma unroll
        for (int l = 0; l < LL; ++l) { e[l] = __expf(s2p[l] * 0.07071067811865475f - mx); sum += e[l]; }
        const float inv = 1.f / sum;
        #pragma unroll
        for (int l = 0; l < LL; ++l) s2p[l] = e[l] * inv;
    }
    __syncthreads();

    {
        const int h = tid;
        float acc = 0.f;
        #pragma unroll
        for (int l = 0; l < LL; ++l) acc = fmaf(s2p[l], mh[l][h], acc);
        out2[(size_t)bs * HID + h] = acc;
    }
}

// ===========================================================================
// FALLBACK PATH (round-3, needs only 3.4 MB ws) — used if ws_size too small
// ===========================================================================

#define XP 330
#define TP 42
#define AP 34

__global__ __launch_bounds__(1024) void transpose_qw(
    const float* __restrict__ qW, short* __restrict__ wqt)
{
    __shared__ float t[32][33];
    const int n = blockIdx.z;
    const int e0 = blockIdx.x * 32, f0 = blockIdx.y * 32;
    const int tx = threadIdx.x, ty = threadIdx.y;
    const int e = e0 + ty, f = f0 + tx;
    t[ty][tx] = (e < EE && f < EE) ? qW[(size_t)n * EE * EE + e * EE + f] : 0.f;
    __syncthreads();
    const int fo = f0 + ty, eo = e0 + tx;
    if (fo < 304)
        wqt[(size_t)n * 304 * 320 + fo * 320 + eo] = f2b(t[tx][ty]);
}

__global__ void conv_vw(const float* __restrict__ vW, short* __restrict__ wvt) {
    int idx = blockIdx.x * 256 + threadIdx.x;
    if (idx >= NH * VD * 320) return;
    int e = idx % 320;
    int v = (idx / 320) % VD;
    int n = idx / (320 * VD);
    wvt[idx] = (e < EE) ? f2b(vW[(size_t)n * EE * VD + e * VD + v]) : (short)0;
}

__global__ __launch_bounds__(512) void nrms_attn_mfma(
    const int*   __restrict__ news,
    const float* __restrict__ emb,
    const short* __restrict__ wqt,
    const float* __restrict__ qB,
    const short* __restrict__ wvt,
    const float* __restrict__ vB,
    float*       __restrict__ out1)
{
    const int bs   = blockIdx.x;
    const int tid  = threadIdx.x;
    const int wave = tid >> 6;
    const int lane = tid & 63;
    const int lr   = lane & 15;
    const int lg   = lane >> 4;

    __shared__ short xs[32][XP];
    __shared__ short xT[320][TP];
    __shared__ short qs[32][XP];
    __shared__ float sc[32][33];
    __shared__ short at[32][AP];

    {
        int* z = (int*)&xs[0][0];
        for (int i = tid; i < 32 * XP / 2; i += 512) z[i] = 0;
        z = (int*)&qs[0][0];
        for (int i = tid; i < 32 * XP / 2; i += 512) z[i] = 0;
        z = (int*)&xT[0][0];
        for (int i = tid; i < 320 * TP / 2; i += 512) z[i] = 0;
    }
    __syncthreads();

    for (int idx = tid; idx < LL * 75; idx += 512) {
        const int l = idx / 75, e4 = (idx % 75) * 4;
        const int row = news[bs * LL + l];
        const float4 v = *reinterpret_cast<const float4*>(emb + (size_t)row * EE + e4);
        const short b0 = f2b(v.x), b1 = f2b(v.y), b2 = f2b(v.z), b3 = f2b(v.w);
        xs[l][e4] = b0; xs[l][e4 + 1] = b1; xs[l][e4 + 2] = b2; xs[l][e4 + 3] = b3;
        xT[e4][l] = b0; xT[e4 + 1][l] = b1; xT[e4 + 2][l] = b2; xT[e4 + 3][l] = b3;
    }
    __syncthreads();

    for (int n = 0; n < NH; ++n) {
        const short* wq = wqt + (size_t)n * 304 * 320;

        for (int p = wave; p < 19; p += 8) {
            f32x4 acc0 = {0.f, 0.f, 0.f, 0.f};
            f32x4 acc1 = {0.f, 0.f, 0.f, 0.f};
            const short* a0p = &xs[lr][lg * 8];
            const short* a1p = &xs[16 + lr][lg * 8];
            const short* bp  = wq + (p * 16 + lr) * 320 + lg * 8;
            #pragma unroll
            for (int k = 0; k < 10; ++k) {
                bf16x8 b  = *reinterpret_cast<const bf16x8*>(bp + k * 32);
                bf16x8 a0 = *reinterpret_cast<const bf16x8*>(a0p + k * 32);
                bf16x8 a1 = *reinterpret_cast<const bf16x8*>(a1p + k * 32);
                acc0 = __builtin_amdgcn_mfma_f32_16x16x32_bf16(a0, b, acc0, 0, 0, 0);
                acc1 = __builtin_amdgcn_mfma_f32_16x16x32_bf16(a1, b, acc1, 0, 0, 0);
            }
            const int col = p * 16 + lr;
            const float bias = (col < EE) ? qB[n * EE + col] : 0.f;
            #pragma unroll
            for (int r = 0; r < 4; ++r) {
                qs[lg * 4 + r][col]      = f2b(acc0[r] + bias);
                qs[16 + lg * 4 + r][col] = f2b(acc1[r] + bias);
            }
        }
        __syncthreads();

        if (wave < 4) {
            const int mt = wave & 1, nt = wave >> 1;
            f32x4 acc = {0.f, 0.f, 0.f, 0.f};
            const short* ap = &qs[mt * 16 + lr][lg * 8];
            const short* bp = &xs[nt * 16 + lr][lg * 8];
            #pragma unroll
            for (int k = 0; k < 10; ++k) {
                bf16x8 a = *reinterpret_cast<const bf16x8*>(ap + k * 32);
                bf16x8 b = *reinterpret_cast<const bf16x8*>(bp + k * 32);
                acc = __builtin_amdgcn_mfma_f32_16x16x32_bf16(a, b, acc, 0, 0, 0);
            }
            #pragma unroll
            for (int r = 0; r < 4; ++r)
                sc[mt * 16 + lg * 4 + r][nt * 16 + lr] = acc[r] * 0.057735026918962584f;
        }
        __syncthreads();

        if (tid < LL) {
            float mx = -1e30f;
            #pragma unroll
            for (int m = 0; m < LL; ++m) mx = fmaxf(mx, sc[tid][m]);
            float ev[LL], sum = 0.f;
            #pragma unroll
            for (int m = 0; m < LL; ++m) { ev[m] = __expf(sc[tid][m] - mx); sum += ev[m]; }
            const float inv = 1.f / sum;
            #pragma unroll
            for (int m = 0; m < LL; ++m) at[tid][m] = f2b(ev[m] * inv);
            #pragma unroll
            for (int m = LL; m < 32; ++m) at[tid][m] = 0;
        } else if (tid < 32) {
            int* zr = (int*)&at[tid][0];
            #pragma unroll
            for (int m = 0; m < 16; ++m) zr[m] = 0;
        }
        __syncthreads();

        for (int p = wave; p < 19; p += 8) {
            bf16x8 b  = *reinterpret_cast<const bf16x8*>(&xT[p * 16 + lr][lg * 8]);
            bf16x8 a0 = *reinterpret_cast<const bf16x8*>(&at[lr][lg * 8]);
            bf16x8 a1 = *reinterpret_cast<const bf16x8*>(&at[16 + lr][lg * 8]);
            f32x4 z = {0.f, 0.f, 0.f, 0.f};
            f32x4 c0 = __builtin_amdgcn_mfma_f32_16x16x32_bf16(a0, b, z, 0, 0, 0);
            f32x4 c1 = __builtin_amdgcn_mfma_f32_16x16x32_bf16(a1, b, z, 0, 0, 0);
            const int col = p * 16 + lr;
            #pragma unroll
            for (int r = 0; r < 4; ++r) {
                qs[lg * 4 + r][col]      = f2b(c0[r]);
                qs[16 + lg * 4 + r][col] = f2b(c1[r]);
            }
        }
        __syncthreads();

        if (wave < 2) {
            const int mt = wave;
            f32x4 acc = {0.f, 0.f, 0.f, 0.f};
            const short* ap = &qs[mt * 16 + lr][lg * 8];
            const short* bp = wvt + (size_t)n * VD * 320 + lr * 320 + lg * 8;
            #pragma unroll
            for (int k = 0; k < 10; ++k) {
                bf16x8 a = *reinterpret_cast<const bf16x8*>(ap + k * 32);
                bf16x8 b = *reinterpret_cast<const bf16x8*>(bp + k * 32);
                acc = __builtin_amdgcn_mfma_f32_16x16x32_bf16(a, b, acc, 0, 0, 0);
            }
            #pragma unroll
            for (int r = 0; r < 4; ++r) {
                const int row = mt * 16 + lg * 4 + r;
                if (row < LL)
                    out1[((size_t)bs * LL + row) * HID + n * VD + lr] = acc[r] + vB[n * VD + lr];
            }
        }
        __syncthreads();
    }
}

// ===========================================================================

extern "C" void kernel_launch(void* const* d_in, const int* in_sizes, int n_in,
                              void* d_out, int out_size, void* d_ws, size_t ws_size,
                              hipStream_t stream) {
    const int*   news  = (const int*)d_in[0];
    const float* emb   = (const float*)d_in[1];
    const float* qW    = (const float*)d_in[2];
    const float* qB    = (const float*)d_in[3];
    const float* vW    = (const float*)d_in[4];
    const float* vB    = (const float*)d_in[5];
    const float* keyW  = (const float*)d_in[6];
    const float* keyB  = (const float*)d_in[7];
    const float* query = (const float*)d_in[8];

    float* out1 = (float*)d_out;            // news_embedding: 8192000 floats
    float* out2 = out1 + 8192000;           // news_repr: 409600 floats

    const size_t NEED = ((size_t)10240000 + 1638400 + 81920 + 8192000 + 53248) * 2;

    if (ws_size >= NEED) {
        short* Xb  = (short*)d_ws;                  // 32000*320
        short* WqT = Xb + 10240000;                 // 16*320*320
        short* WvT = WqT + 1638400;                 // 256*320
        short* xv  = WvT + 81920;                   // 32000*256
        short* kwb = xv + 8192000;                  // 208*256

        hipLaunchKernelGGL(build_xb, dim3(10000), dim3(256), 0, stream, news, emb, Xb);
        hipLaunchKernelGGL(build_wqt, dim3(10, 10, 16), dim3(32, 32), 0, stream, qW, qB, WqT);
        hipLaunchKernelGGL(build_wvt, dim3(320), dim3(256), 0, stream, vW, vB, WvT);
        hipLaunchKernelGGL(conv_kw, dim3(208), dim3(256), 0, stream, keyW, kwb);
        hipLaunchKernelGGL(gemm_xv, dim3(2, 250), dim3(256), 0, stream, Xb, WvT, xv);
        hipLaunchKernelGGL(qattn, dim3(800, 16), dim3(512), 0, stream, Xb, WqT, xv, out1);
        hipLaunchKernelGGL(nrms_pool_mfma, dim3(NBS), dim3(256), 0, stream,
                           out1, kwb, keyB, query, out2);
    } else {
        short* wqt = (short*)d_ws;
        short* wvt = wqt + (size_t)NH * 304 * 320;
        short* kwb = wvt + (size_t)NH * VD * 320;

        hipLaunchKernelGGL(transpose_qw, dim3(10, 10, 16), dim3(32, 32), 0, stream, qW, wqt);
        hipLaunchKernelGGL(conv_vw, dim3(320), dim3(256), 0, stream, vW, wvt);
        hipLaunchKernelGGL(conv_kw, dim3(208), dim3(256), 0, stream, keyW, kwb);
        hipLaunchKernelGGL(nrms_attn_mfma, dim3(NBS), dim3(512), 0, stream,
                           news, emb, wqt, qB, wvt, vB, out1);
        hipLaunchKernelGGL(nrms_pool_mfma, dim3(NBS), dim3(256), 0, stream,
                           out1, kwb, keyB, query, out2);
    }
}

// Round 7
// 418.467 us; speedup vs baseline: 1.0650x; 1.0650x over previous
//
#include <hip/hip_runtime.h>
#include <math.h>

#define NBS 1600      // B*S
#define LL 20
#define EE 300
#define NH 16
#define VD 16
#define HID 256
#define QD 200

typedef short bf16x8 __attribute__((ext_vector_type(8)));
typedef float f32x4 __attribute__((ext_vector_type(4)));

__device__ __forceinline__ short f2b(float f) {
    union { float f; unsigned u; } c; c.f = f;
    unsigned r = (c.u + 0x7FFFu + ((c.u >> 16) & 1u)) >> 16;  // RNE
    return (short)r;
}

__device__ __forceinline__ float ftanh(float a) {
    a = fminf(fmaxf(a, -15.f), 15.f);
    float t = __expf(2.f * a);
    return (t - 1.f) / (t + 1.f);
}

// ===========================================================================
// NEW PATH (needs ~40.4 MB ws)
// ===========================================================================

// news/emb -> Xb bf16 [32000][320]; col300 = 1.0 (bias channel), 301..319 = 0
__global__ void build_xb(const int* __restrict__ news, const float* __restrict__ emb,
                         short* __restrict__ Xb) {
    int idx = blockIdx.x * 256 + threadIdx.x;     // one per 4 elems
    if (idx >= 32000 * 80) return;
    int i = idx / 80, e4 = (idx % 80) * 4;
    short4 o;
    if (e4 < 300) {
        const float4 v = *reinterpret_cast<const float4*>(emb + (size_t)news[i] * EE + e4);
        o.x = f2b(v.x); o.y = f2b(v.y); o.z = f2b(v.z); o.w = f2b(v.w);
    } else if (e4 == 300) {
        o.x = (short)0x3F80; o.y = 0; o.z = 0; o.w = 0;
    } else {
        o.x = o.y = o.z = o.w = 0;
    }
    *reinterpret_cast<short4*>(Xb + (size_t)i * 320 + e4) = o;
}

// Wq [n][e][f] -> WqT bf16 [n][f(320)][e(320)], col300 = qB, zero rows f>=300
__global__ __launch_bounds__(1024) void build_wqt(
    const float* __restrict__ qW, const float* __restrict__ qB, short* __restrict__ WqT)
{
    __shared__ float t[32][33];
    const int n = blockIdx.z;
    const int e0 = blockIdx.x * 32, f0 = blockIdx.y * 32;
    const int tx = threadIdx.x, ty = threadIdx.y;
    const int e = e0 + ty, f = f0 + tx;
    t[ty][tx] = (e < EE && f < EE) ? qW[((size_t)n * EE + e) * EE + f] : 0.f;
    __syncthreads();
    const int fo = f0 + ty, eo = e0 + tx;
    float val;
    if (fo >= EE)      val = 0.f;
    else if (eo < EE)  val = t[tx][ty];
    else if (eo == EE) val = qB[n * EE + fo];
    else               val = 0.f;
    WqT[((size_t)n * 320 + fo) * 320 + eo] = f2b(val);
}

// Wv [n][e][v] -> WvT bf16 [256][320] rows c=n*16+vd, col300 = vB
__global__ void build_wvt(const float* __restrict__ vW, const float* __restrict__ vB,
                          short* __restrict__ WvT) {
    int idx = blockIdx.x * 256 + threadIdx.x;
    if (idx >= 256 * 320) return;
    int c = idx / 320, e = idx % 320;
    int n = c >> 4, vd = c & 15;
    float val = (e < EE) ? vW[((size_t)n * EE + e) * VD + vd]
                         : (e == EE ? vB[n * VD + vd] : 0.f);
    WvT[idx] = f2b(val);
}

// keyW [200][256] fp32 -> bf16 [208][256] (rows >=200 zero)
__global__ void conv_kw(const float* __restrict__ keyW, short* __restrict__ kwb) {
    int idx = blockIdx.x * 256 + threadIdx.x;
    if (idx >= 208 * 256) return;
    int d = idx >> 8;
    kwb[idx] = (d < QD) ? f2b(keyW[idx]) : (short)0;
}

// xv = Xb * WvT^T : [32000][256] bf16.  128x128 tile, 4 waves.
__global__ __launch_bounds__(256) void gemm_xv(
    const short* __restrict__ Xb, const short* __restrict__ WvT, short* __restrict__ xv)
{
    const int nt0 = blockIdx.x * 128;
    const size_t mt0 = (size_t)blockIdx.y * 128;
    const int tid = threadIdx.x, wave = tid >> 6, lane = tid & 63;
    const int lr = lane & 15, lg = lane >> 4;
    const int wm = wave & 1, wn = wave >> 1;

    __shared__ short As[128][68];
    __shared__ short Bs[128][68];
    f32x4 acc[4][4] = {};

    for (int ks = 0; ks < 5; ++ks) {
        __syncthreads();
        for (int u = 0; u < 4; ++u) {
            int idx = u * 256 + tid;          // 0..1023
            int rr = idx >> 3, c8 = idx & 7;
            *reinterpret_cast<bf16x8*>(&As[rr][c8 * 8]) =
                *reinterpret_cast<const bf16x8*>(Xb + (mt0 + rr) * 320 + ks * 64 + c8 * 8);
            *reinterpret_cast<bf16x8*>(&Bs[rr][c8 * 8]) =
                *reinterpret_cast<const bf16x8*>(WvT + (size_t)(nt0 + rr) * 320 + ks * 64 + c8 * 8);
        }
        __syncthreads();
        #pragma unroll
        for (int kk = 0; kk < 2; ++kk) {
            bf16x8 af[4], bfv[4];
            #pragma unroll
            for (int f = 0; f < 4; ++f)
                af[f] = *reinterpret_cast<const bf16x8*>(&As[wm * 64 + f * 16 + lr][kk * 32 + lg * 8]);
            #pragma unroll
            for (int f = 0; f < 4; ++f)
                bfv[f] = *reinterpret_cast<const bf16x8*>(&Bs[wn * 64 + f * 16 + lr][kk * 32 + lg * 8]);
            #pragma unroll
            for (int i = 0; i < 4; ++i)
                #pragma unroll
                for (int j = 0; j < 4; ++j)
                    acc[i][j] = __builtin_amdgcn_mfma_f32_16x16x32_bf16(af[i], bfv[j], acc[i][j], 0, 0, 0);
        }
    }
    #pragma unroll
    for (int i = 0; i < 4; ++i)
        #pragma unroll
        for (int j = 0; j < 4; ++j)
            #pragma unroll
            for (int r = 0; r < 4; ++r)
                xv[(mt0 + wm * 64 + i * 16 + lg * 4 + r) * 256 + nt0 + wn * 64 + j * 16 + lr]
                    = f2b(acc[i][j][r]);
}

// ---------------------------------------------------------------------------
// qattn v4: one block per (160 rows = 8 bs, head). 512 threads, 8 waves.
// q-GEMM M=160 x N=320 x K=320: wave tile 80x80 (5x5 acc, 25 MFMA/K-step).
// A/B reg-staged to LDS (stride 36 = 18dw, bank-uniform b128), T14 split.
// Fused scores/softmax/v: one wave per bs (8 bs in parallel).
// LDS 153 KB -> 1 block/CU.
// ---------------------------------------------------------------------------
__global__ __launch_bounds__(512, 2) void qattn(
    const short* __restrict__ Xb,    // [32000][320]
    const short* __restrict__ WqT,   // [16][320][320]
    const short* __restrict__ xv,    // [32000][256]
    float*       __restrict__ out1)  // [32000][256]
{
    const int g = blockIdx.x;        // 160-row chunk (8 bs)
    const int n = blockIdx.y;        // head
    const int tid = threadIdx.x, wave = tid >> 6, lane = tid & 63;
    const int lr = lane & 15, lg = lane >> 4;
    const int wm = wave >> 2, wn = wave & 3;
    const size_t row0 = (size_t)g * 160;

    __shared__ short qs[160][328];   // q tile (164dw stride, bank-uniform)
    __shared__ short Asg[160][36];   // X K-chunk (18dw stride)
    __shared__ short Bsg[320][36];   // WqT K-chunk
    __shared__ short atw[8][32][34]; // per-bs attn (pads zero)

    // zero atw
    for (int i = tid; i < 4352; i += 512) reinterpret_cast<int*>(atw)[i] = 0;

    const short* wh = WqT + (size_t)n * 320 * 320;

    // staging roles: threads 0..159 -> A row tid; 160..479 -> B row tid-160
    const bool isA = tid < 160;
    const bool stg = tid < 480;
    const short* gsrc = isA ? (Xb + (row0 + tid) * 320)
                            : (wh + (size_t)(stg ? tid - 160 : 0) * 320);
    short* ldst = isA ? &Asg[tid][0] : &Bsg[stg ? tid - 160 : 0][0];

    // prefetch staging chunk 0
    bf16x8 st0, st1, st2, st3;
    if (stg) {
        st0 = *reinterpret_cast<const bf16x8*>(gsrc);
        st1 = *reinterpret_cast<const bf16x8*>(gsrc + 8);
        st2 = *reinterpret_cast<const bf16x8*>(gsrc + 16);
        st3 = *reinterpret_cast<const bf16x8*>(gsrc + 24);
    }

    // prefetch xv B-frag for v-phase (wave = bs)
    bf16x8 bv;
    {
        const int b = wave;
        #pragma unroll
        for (int j = 0; j < 8; ++j) {
            int m = lg * 8 + j; if (m > 19) m = 19;   // attn cols >=20 are zero
            bv[j] = xv[(row0 + b * 20 + m) * 256 + n * 16 + lr];
        }
    }

    // ---- q-GEMM K-loop ----
    f32x4 acc[5][5] = {};
    for (int ks = 0; ks < 10; ++ks) {
        __syncthreads();                       // stage buffers free
        if (stg) {
            *reinterpret_cast<bf16x8*>(ldst)      = st0;
            *reinterpret_cast<bf16x8*>(ldst + 8)  = st1;
            *reinterpret_cast<bf16x8*>(ldst + 16) = st2;
            *reinterpret_cast<bf16x8*>(ldst + 24) = st3;
        }
        __syncthreads();                       // stage ready
        if (ks < 9 && stg) {                   // issue next chunk (flies over MFMAs)
            const short* s = gsrc + (ks + 1) * 32;
            st0 = *reinterpret_cast<const bf16x8*>(s);
            st1 = *reinterpret_cast<const bf16x8*>(s + 8);
            st2 = *reinterpret_cast<const bf16x8*>(s + 16);
            st3 = *reinterpret_cast<const bf16x8*>(s + 24);
        }
        bf16x8 af[5], bfr[5];
        #pragma unroll
        for (int i = 0; i < 5; ++i)
            af[i] = *reinterpret_cast<const bf16x8*>(&Asg[wm * 80 + i * 16 + lr][lg * 8]);
        #pragma unroll
        for (int j = 0; j < 5; ++j)
            bfr[j] = *reinterpret_cast<const bf16x8*>(&Bsg[wn * 80 + j * 16 + lr][lg * 8]);
        #pragma unroll
        for (int i = 0; i < 5; ++i)
            #pragma unroll
            for (int j = 0; j < 5; ++j)
                acc[i][j] = __builtin_amdgcn_mfma_f32_16x16x32_bf16(af[i], bfr[j], acc[i][j], 0, 0, 0);
    }

    // ---- acc -> qs (bf16) ----
    #pragma unroll
    for (int i = 0; i < 5; ++i)
        #pragma unroll
        for (int j = 0; j < 5; ++j)
            #pragma unroll
            for (int r = 0; r < 4; ++r)
                qs[wm * 80 + i * 16 + lg * 4 + r][wn * 80 + j * 16 + lr] = f2b(acc[i][j][r]);
    __syncthreads();

    // ---- scores + in-register softmax: wave = bs ----
    {
        const int b = wave;
        const int rA0 = b * 20 + lr;                         // <=155, real
        int rA1 = b * 20 + 16 + lr; if (rA1 > 159) rA1 = 159;
        const size_t rB0 = row0 + b * 20 + lr;
        size_t rB1 = row0 + b * 20 + 16 + lr; if (rB1 > 31999) rB1 = 31999;

        f32x4 s[2][2] = {};
        bf16x8 xb0 = *reinterpret_cast<const bf16x8*>(Xb + rB0 * 320 + lg * 8);
        bf16x8 xb1 = *reinterpret_cast<const bf16x8*>(Xb + rB1 * 320 + lg * 8);
        #pragma unroll
        for (int ks = 0; ks < 10; ++ks) {
            bf16x8 x0c = xb0, x1c = xb1;
            if (ks < 9) {
                const int kc = (ks + 1) * 32 + lg * 8;
                xb0 = *reinterpret_cast<const bf16x8*>(Xb + rB0 * 320 + kc);
                xb1 = *reinterpret_cast<const bf16x8*>(Xb + rB1 * 320 + kc);
            }
            const int kc = ks * 32 + lg * 8;
            bf16x8 a0 = *reinterpret_cast<const bf16x8*>(&qs[rA0][kc]);
            bf16x8 a1 = *reinterpret_cast<const bf16x8*>(&qs[rA1][kc]);
            s[0][0] = __builtin_amdgcn_mfma_f32_16x16x32_bf16(a0, x0c, s[0][0], 0, 0, 0);
            s[0][1] = __builtin_amdgcn_mfma_f32_16x16x32_bf16(a0, x1c, s[0][1], 0, 0, 0);
            s[1][0] = __builtin_amdgcn_mfma_f32_16x16x32_bf16(a1, x0c, s[1][0], 0, 0, 0);
            s[1][1] = __builtin_amdgcn_mfma_f32_16x16x32_bf16(a1, x1c, s[1][1], 0, 0, 0);
        }

        const float scl = 0.057735026918962584f;  // 1/sqrt(300)
        #pragma unroll
        for (int mts = 0; mts < 2; ++mts) {
            #pragma unroll
            for (int r = 0; r < 4; ++r) {
                float v0 = s[mts][0][r] * scl;
                float v1 = s[mts][1][r] * scl;
                float mx = (lr < 4) ? fmaxf(v0, v1) : v0;
                mx = fmaxf(mx, __shfl_xor(mx, 1));
                mx = fmaxf(mx, __shfl_xor(mx, 2));
                mx = fmaxf(mx, __shfl_xor(mx, 4));
                mx = fmaxf(mx, __shfl_xor(mx, 8));
                float e0 = __expf(v0 - mx);
                float e1 = (lr < 4) ? __expf(v1 - mx) : 0.f;
                float sm = e0 + e1;
                sm += __shfl_xor(sm, 1);
                sm += __shfl_xor(sm, 2);
                sm += __shfl_xor(sm, 4);
                sm += __shfl_xor(sm, 8);
                const float inv = 1.f / sm;
                const int row = mts * 16 + lg * 4 + r;
                if (row < LL) {
                    atw[b][row][lr]      = f2b(e0 * inv);
                    atw[b][row][16 + lr] = f2b(e1 * inv);   // lr>=4 writes 0
                }
            }
        }
    }
    __syncthreads();

    // ---- v = attn * xv : wave = bs, both mt tiles ----
    {
        const int b = wave;
        bf16x8 va0 = *reinterpret_cast<const bf16x8*>(&atw[b][lr][lg * 8]);
        bf16x8 va1 = *reinterpret_cast<const bf16x8*>(&atw[b][16 + lr][lg * 8]);
        f32x4 z = {0.f, 0.f, 0.f, 0.f};
        f32x4 v0 = __builtin_amdgcn_mfma_f32_16x16x32_bf16(va0, bv, z, 0, 0, 0);
        f32x4 v1 = __builtin_amdgcn_mfma_f32_16x16x32_bf16(va1, bv, z, 0, 0, 0);
        #pragma unroll
        for (int r = 0; r < 4; ++r) {
            const int rowl = lg * 4 + r;
            out1[(row0 + b * 20 + rowl) * 256 + n * 16 + lr] = v0[r];
            const int rowl1 = 16 + lg * 4 + r;
            if (rowl1 < LL)
                out1[(row0 + b * 20 + rowl1) * 256 + n * 16 + lr] = v1[r];
        }
    }
}

// ---------------------------------------------------------------------------
// Additive attention pooling per bs, MFMA add_key. grid 1600, block 256.
// ---------------------------------------------------------------------------
__global__ __launch_bounds__(256) void nrms_pool_mfma(
    const float* __restrict__ out1,
    const short* __restrict__ kwb,    // [208][256] bf16
    const float* __restrict__ keyB,   // [200]
    const float* __restrict__ query,  // [200]
    float*       __restrict__ out2)   // [NBS][256]
{
    const int bs   = blockIdx.x;
    const int tid  = threadIdx.x;
    const int wave = tid >> 6;
    const int lane = tid & 63;
    const int lr   = lane & 15;
    const int lg   = lane >> 4;

    __shared__ float mh[LL][257];
    __shared__ short mhb[32][264];   // 132 dw == 4 mod 32
    __shared__ float s2p[32];

    for (int i = tid; i < 12 * 128; i += 256) {
        const int r = 20 + i / 128, c = (i % 128) * 2;
        *reinterpret_cast<int*>(&mhb[r][c]) = 0;
    }
    if (tid < 32) s2p[tid] = 0.f;

    for (int idx = tid; idx < LL * 64; idx += 256) {
        const int l = idx >> 6, h4 = (idx & 63) * 4;
        const float4 v = *reinterpret_cast<const float4*>(out1 + ((size_t)bs * LL + l) * HID + h4);
        mh[l][h4] = v.x; mh[l][h4 + 1] = v.y; mh[l][h4 + 2] = v.z; mh[l][h4 + 3] = v.w;
        mhb[l][h4] = f2b(v.x); mhb[l][h4 + 1] = f2b(v.y);
        mhb[l][h4 + 2] = f2b(v.z); mhb[l][h4 + 3] = f2b(v.w);
    }
    __syncthreads();

    for (int t = wave; t < 26; t += 4) {
        const int mt = t & 1, nt = t >> 1;
        f32x4 acc = {0.f, 0.f, 0.f, 0.f};
        const short* ap = &mhb[mt * 16 + lr][lg * 8];
        const short* bp = kwb + (nt * 16 + lr) * 256 + lg * 8;
        #pragma unroll
        for (int k = 0; k < 8; ++k) {
            bf16x8 a = *reinterpret_cast<const bf16x8*>(ap + k * 32);
            bf16x8 b = *reinterpret_cast<const bf16x8*>(bp + k * 32);
            acc = __builtin_amdgcn_mfma_f32_16x16x32_bf16(a, b, acc, 0, 0, 0);
        }
        const int d = nt * 16 + lr;
        const float qd = (d < QD) ? query[d] : 0.f;
        const float kb = (d < QD) ? keyB[d] : 0.f;
        float vals[4];
        #pragma unroll
        for (int r = 0; r < 4; ++r) vals[r] = qd * ftanh(acc[r] + kb);
        #pragma unroll
        for (int off = 1; off < 16; off <<= 1) {
            #pragma unroll
            for (int r = 0; r < 4; ++r) vals[r] += __shfl_xor(vals[r], off);
        }
        if (lr == 0) {
            #pragma unroll
            for (int r = 0; r < 4; ++r)
                atomicAdd(&s2p[mt * 16 + lg * 4 + r], vals[r]);
        }
    }
    __syncthreads();

    if (tid == 0) {
        float mx = -1e30f;
        #pragma unroll
        for (int l = 0; l < LL; ++l) mx = fmaxf(mx, s2p[l] * 0.07071067811865475f);
        float sum = 0.f;
        float e[LL];
        #pragma unroll
        for (int l = 0; l < LL; ++l) { e[l] = __expf(s2p[l] * 0.07071067811865475f - mx); sum += e[l]; }
        const float inv = 1.f / sum;
        #pragma unroll
        for (int l = 0; l < LL; ++l) s2p[l] = e[l] * inv;
    }
    __syncthreads();

    {
        const int h = tid;
        float acc = 0.f;
        #pragma unroll
        for (int l = 0; l < LL; ++l) acc = fmaf(s2p[l], mh[l][h], acc);
        out2[(size_t)bs * HID + h] = acc;
    }
}

// ===========================================================================
// FALLBACK PATH (round-3, needs only 3.4 MB ws) — used if ws_size too small
// ===========================================================================

#define XP 330
#define TP 42
#define AP 34

__global__ __launch_bounds__(1024) void transpose_qw(
    const float* __restrict__ qW, short* __restrict__ wqt)
{
    __shared__ float t[32][33];
    const int n = blockIdx.z;
    const int e0 = blockIdx.x * 32, f0 = blockIdx.y * 32;
    const int tx = threadIdx.x, ty = threadIdx.y;
    const int e = e0 + ty, f = f0 + tx;
    t[ty][tx] = (e < EE && f < EE) ? qW[(size_t)n * EE * EE + e * EE + f] : 0.f;
    __syncthreads();
    const int fo = f0 + ty, eo = e0 + tx;
    if (fo < 304)
        wqt[(size_t)n * 304 * 320 + fo * 320 + eo] = f2b(t[tx][ty]);
}

__global__ void conv_vw(const float* __restrict__ vW, short* __restrict__ wvt) {
    int idx = blockIdx.x * 256 + threadIdx.x;
    if (idx >= NH * VD * 320) return;
    int e = idx % 320;
    int v = (idx / 320) % VD;
    int n = idx / (320 * VD);
    wvt[idx] = (e < EE) ? f2b(vW[(size_t)n * EE * VD + e * VD + v]) : (short)0;
}

__global__ __launch_bounds__(512) void nrms_attn_mfma(
    const int*   __restrict__ news,
    const float* __restrict__ emb,
    const short* __restrict__ wqt,
    const float* __restrict__ qB,
    const short* __restrict__ wvt,
    const float* __restrict__ vB,
    float*       __restrict__ out1)
{
    const int bs   = blockIdx.x;
    const int tid  = threadIdx.x;
    const int wave = tid >> 6;
    const int lane = tid & 63;
    const int lr   = lane & 15;
    const int lg   = lane >> 4;

    __shared__ short xs[32][XP];
    __shared__ short xT[320][TP];
    __shared__ short qs[32][XP];
    __shared__ float sc[32][33];
    __shared__ short at[32][AP];

    {
        int* z = (int*)&xs[0][0];
        for (int i = tid; i < 32 * XP / 2; i += 512) z[i] = 0;
        z = (int*)&qs[0][0];
        for (int i = tid; i < 32 * XP / 2; i += 512) z[i] = 0;
        z = (int*)&xT[0][0];
        for (int i = tid; i < 320 * TP / 2; i += 512) z[i] = 0;
    }
    __syncthreads();

    for (int idx = tid; idx < LL * 75; idx += 512) {
        const int l = idx / 75, e4 = (idx % 75) * 4;
        const int row = news[bs * LL + l];
        const float4 v = *reinterpret_cast<const float4*>(emb + (size_t)row * EE + e4);
        const short b0 = f2b(v.x), b1 = f2b(v.y), b2 = f2b(v.z), b3 = f2b(v.w);
        xs[l][e4] = b0; xs[l][e4 + 1] = b1; xs[l][e4 + 2] = b2; xs[l][e4 + 3] = b3;
        xT[e4][l] = b0; xT[e4 + 1][l] = b1; xT[e4 + 2][l] = b2; xT[e4 + 3][l] = b3;
    }
    __syncthreads();

    for (int n = 0; n < NH; ++n) {
        const short* wq = wqt + (size_t)n * 304 * 320;

        for (int p = wave; p < 19; p += 8) {
            f32x4 acc0 = {0.f, 0.f, 0.f, 0.f};
            f32x4 acc1 = {0.f, 0.f, 0.f, 0.f};
            const short* a0p = &xs[lr][lg * 8];
            const short* a1p = &xs[16 + lr][lg * 8];
            const short* bp  = wq + (p * 16 + lr) * 320 + lg * 8;
            #pragma unroll
            for (int k = 0; k < 10; ++k) {
                bf16x8 b  = *reinterpret_cast<const bf16x8*>(bp + k * 32);
                bf16x8 a0 = *reinterpret_cast<const bf16x8*>(a0p + k * 32);
                bf16x8 a1 = *reinterpret_cast<const bf16x8*>(a1p + k * 32);
                acc0 = __builtin_amdgcn_mfma_f32_16x16x32_bf16(a0, b, acc0, 0, 0, 0);
                acc1 = __builtin_amdgcn_mfma_f32_16x16x32_bf16(a1, b, acc1, 0, 0, 0);
            }
            const int col = p * 16 + lr;
            const float bias = (col < EE) ? qB[n * EE + col] : 0.f;
            #pragma unroll
            for (int r = 0; r < 4; ++r) {
                qs[lg * 4 + r][col]      = f2b(acc0[r] + bias);
                qs[16 + lg * 4 + r][col] = f2b(acc1[r] + bias);
            }
        }
        __syncthreads();

        if (wave < 4) {
            const int mt = wave & 1, nt = wave >> 1;
            f32x4 acc = {0.f, 0.f, 0.f, 0.f};
            const short* ap = &qs[mt * 16 + lr][lg * 8];
            const short* bp = &xs[nt * 16 + lr][lg * 8];
            #pragma unroll
            for (int k = 0; k < 10; ++k) {
                bf16x8 a = *reinterpret_cast<const bf16x8*>(ap + k * 32);
                bf16x8 b = *reinterpret_cast<const bf16x8*>(bp + k * 32);
                acc = __builtin_amdgcn_mfma_f32_16x16x32_bf16(a, b, acc, 0, 0, 0);
            }
            #pragma unroll
            for (int r = 0; r < 4; ++r)
                sc[mt * 16 + lg * 4 + r][nt * 16 + lr] = acc[r] * 0.057735026918962584f;
        }
        __syncthreads();

        if (tid < LL) {
            float mx = -1e30f;
            #pragma unroll
            for (int m = 0; m < LL; ++m) mx = fmaxf(mx, sc[tid][m]);
            float ev[LL], sum = 0.f;
            #pragma unroll
            for (int m = 0; m < LL; ++m) { ev[m] = __expf(sc[tid][m] - mx); sum += ev[m]; }
            const float inv = 1.f / sum;
            #pragma unroll
            for (int m = 0; m < LL; ++m) at[tid][m] = f2b(ev[m] * inv);
            #pragma unroll
            for (int m = LL; m < 32; ++m) at[tid][m] = 0;
        } else if (tid < 32) {
            int* zr = (int*)&at[tid][0];
            #pragma unroll
            for (int m = 0; m < 16; ++m) zr[m] = 0;
        }
        __syncthreads();

        for (int p = wave; p < 19; p += 8) {
            bf16x8 b  = *reinterpret_cast<const bf16x8*>(&xT[p * 16 + lr][lg * 8]);
            bf16x8 a0 = *reinterpret_cast<const bf16x8*>(&at[lr][lg * 8]);
            bf16x8 a1 = *reinterpret_cast<const bf16x8*>(&at[16 + lr][lg * 8]);
            f32x4 z = {0.f, 0.f, 0.f, 0.f};
            f32x4 c0 = __builtin_amdgcn_mfma_f32_16x16x32_bf16(a0, b, z, 0, 0, 0);
            f32x4 c1 = __builtin_amdgcn_mfma_f32_16x16x32_bf16(a1, b, z, 0, 0, 0);
            const int col = p * 16 + lr;
            #pragma unroll
            for (int r = 0; r < 4; ++r) {
                qs[lg * 4 + r][col]      = f2b(c0[r]);
                qs[16 + lg * 4 + r][col] = f2b(c1[r]);
            }
        }
        __syncthreads();

        if (wave < 2) {
            const int mt = wave;
            f32x4 acc = {0.f, 0.f, 0.f, 0.f};
            const short* ap = &qs[mt * 16 + lr][lg * 8];
            const short* bp = wvt + (size_t)n * VD * 320 + lr * 320 + lg * 8;
            #pragma unroll
            for (int k = 0; k < 10; ++k) {
                bf16x8 a = *reinterpret_cast<const bf16x8*>(ap + k * 32);
                bf16x8 b = *reinterpret_cast<const bf16x8*>(bp + k * 32);
                acc = __builtin_amdgcn_mfma_f32_16x16x32_bf16(a, b, acc, 0, 0, 0);
            }
            #pragma unroll
            for (int r = 0; r < 4; ++r) {
                const int row = mt * 16 + lg * 4 + r;
                if (row < LL)
                    out1[((size_t)bs * LL + row) * HID + n * VD + lr] = acc[r] + vB[n * VD + lr];
            }
        }
        __syncthreads();
    }
}

// ===========================================================================

extern "C" void kernel_launch(void* const* d_in, const int* in_sizes, int n_in,
                              void* d_out, int out_size, void* d_ws, size_t ws_size,
                              hipStream_t stream) {
    const int*   news  = (const int*)d_in[0];
    const float* emb   = (const float*)d_in[1];
    const float* qW    = (const float*)d_in[2];
    const float* qB    = (const float*)d_in[3];
    const float* vW    = (const float*)d_in[4];
    const float* vB    = (const float*)d_in[5];
    const float* keyW  = (const float*)d_in[6];
    const float* keyB  = (const float*)d_in[7];
    const float* query = (const float*)d_in[8];

    float* out1 = (float*)d_out;            // news_embedding: 8192000 floats
    float* out2 = out1 + 8192000;           // news_repr: 409600 floats

    const size_t NEED = ((size_t)10240000 + 1638400 + 81920 + 8192000 + 53248) * 2;

    if (ws_size >= NEED) {
        short* Xb  = (short*)d_ws;                  // 32000*320
        short* WqT = Xb + 10240000;                 // 16*320*320
        short* WvT = WqT + 1638400;                 // 256*320
        short* xv  = WvT + 81920;                   // 32000*256
        short* kwb = xv + 8192000;                  // 208*256

        hipLaunchKernelGGL(build_xb, dim3(10000), dim3(256), 0, stream, news, emb, Xb);
        hipLaunchKernelGGL(build_wqt, dim3(10, 10, 16), dim3(32, 32), 0, stream, qW, qB, WqT);
        hipLaunchKernelGGL(build_wvt, dim3(320), dim3(256), 0, stream, vW, vB, WvT);
        hipLaunchKernelGGL(conv_kw, dim3(208), dim3(256), 0, stream, keyW, kwb);
        hipLaunchKernelGGL(gemm_xv, dim3(2, 250), dim3(256), 0, stream, Xb, WvT, xv);
        hipLaunchKernelGGL(qattn, dim3(200, 16), dim3(512), 0, stream, Xb, WqT, xv, out1);
        hipLaunchKernelGGL(nrms_pool_mfma, dim3(NBS), dim3(256), 0, stream,
                           out1, kwb, keyB, query, out2);
    } else {
        short* wqt = (short*)d_ws;
        short* wvt = wqt + (size_t)NH * 304 * 320;
        short* kwb = wvt + (size_t)NH * VD * 320;

        hipLaunchKernelGGL(transpose_qw, dim3(10, 10, 16), dim3(32, 32), 0, stream, qW, wqt);
        hipLaunchKernelGGL(conv_vw, dim3(320), dim3(256), 0, stream, vW, wvt);
        hipLaunchKernelGGL(conv_kw, dim3(208), dim3(256), 0, stream, keyW, kwb);
        hipLaunchKernelGGL(nrms_attn_mfma, dim3(NBS), dim3(512), 0, stream,
                           news, emb, wqt, qB, wvt, vB, out1);
        hipLaunchKernelGGL(nrms_pool_mfma, dim3(NBS), dim3(256), 0, stream,
                           out1, kwb, keyB, query, out2);
    }
}

// Round 8
// 409.577 us; speedup vs baseline: 1.0881x; 1.0217x over previous
//
#include <hip/hip_runtime.h>
#include <math.h>

#define NBS 1600      // B*S
#define LL 20
#define EE 300
#define NH 16
#define VD 16
#define HID 256
#define QD 200

typedef short bf16x8 __attribute__((ext_vector_type(8)));
typedef float f32x4 __attribute__((ext_vector_type(4)));

__device__ __forceinline__ short f2b(float f) {
    union { float f; unsigned u; } c; c.f = f;
    unsigned r = (c.u + 0x7FFFu + ((c.u >> 16) & 1u)) >> 16;  // RNE
    return (short)r;
}

__device__ __forceinline__ float ftanh(float a) {
    a = fminf(fmaxf(a, -15.f), 15.f);
    float t = __expf(2.f * a);
    return (t - 1.f) / (t + 1.f);
}

// ===========================================================================
// NEW PATH (needs ~40.4 MB ws)
// ===========================================================================

// news/emb -> Xb bf16 [32000][320]; col300 = 1.0 (bias channel), 301..319 = 0
__global__ void build_xb(const int* __restrict__ news, const float* __restrict__ emb,
                         short* __restrict__ Xb) {
    int idx = blockIdx.x * 256 + threadIdx.x;     // one per 4 elems
    if (idx >= 32000 * 80) return;
    int i = idx / 80, e4 = (idx % 80) * 4;
    short4 o;
    if (e4 < 300) {
        const float4 v = *reinterpret_cast<const float4*>(emb + (size_t)news[i] * EE + e4);
        o.x = f2b(v.x); o.y = f2b(v.y); o.z = f2b(v.z); o.w = f2b(v.w);
    } else if (e4 == 300) {
        o.x = (short)0x3F80; o.y = 0; o.z = 0; o.w = 0;
    } else {
        o.x = o.y = o.z = o.w = 0;
    }
    *reinterpret_cast<short4*>(Xb + (size_t)i * 320 + e4) = o;
}

// Wq [n][e][f] -> WqT bf16 [n][f(320)][e(320)], col300 = qB, zero rows f>=300
__global__ __launch_bounds__(1024) void build_wqt(
    const float* __restrict__ qW, const float* __restrict__ qB, short* __restrict__ WqT)
{
    __shared__ float t[32][33];
    const int n = blockIdx.z;
    const int e0 = blockIdx.x * 32, f0 = blockIdx.y * 32;
    const int tx = threadIdx.x, ty = threadIdx.y;
    const int e = e0 + ty, f = f0 + tx;
    t[ty][tx] = (e < EE && f < EE) ? qW[((size_t)n * EE + e) * EE + f] : 0.f;
    __syncthreads();
    const int fo = f0 + ty, eo = e0 + tx;
    float val;
    if (fo >= EE)      val = 0.f;
    else if (eo < EE)  val = t[tx][ty];
    else if (eo == EE) val = qB[n * EE + fo];
    else               val = 0.f;
    WqT[((size_t)n * 320 + fo) * 320 + eo] = f2b(val);
}

// Wv [n][e][v] -> WvT bf16 [256][320] rows c=n*16+vd, col300 = vB
__global__ void build_wvt(const float* __restrict__ vW, const float* __restrict__ vB,
                          short* __restrict__ WvT) {
    int idx = blockIdx.x * 256 + threadIdx.x;
    if (idx >= 256 * 320) return;
    int c = idx / 320, e = idx % 320;
    int n = c >> 4, vd = c & 15;
    float val = (e < EE) ? vW[((size_t)n * EE + e) * VD + vd]
                         : (e == EE ? vB[n * VD + vd] : 0.f);
    WvT[idx] = f2b(val);
}

// keyW [200][256] fp32 -> bf16 [208][256] (rows >=200 zero)
__global__ void conv_kw(const float* __restrict__ keyW, short* __restrict__ kwb) {
    int idx = blockIdx.x * 256 + threadIdx.x;
    if (idx >= 208 * 256) return;
    int d = idx >> 8;
    kwb[idx] = (d < QD) ? f2b(keyW[idx]) : (short)0;
}

// xv = Xb * WvT^T : [32000][256] bf16.  128x128 tile, 4 waves.
__global__ __launch_bounds__(256) void gemm_xv(
    const short* __restrict__ Xb, const short* __restrict__ WvT, short* __restrict__ xv)
{
    const int nt0 = blockIdx.x * 128;
    const size_t mt0 = (size_t)blockIdx.y * 128;
    const int tid = threadIdx.x, wave = tid >> 6, lane = tid & 63;
    const int lr = lane & 15, lg = lane >> 4;
    const int wm = wave & 1, wn = wave >> 1;

    __shared__ short As[128][68];
    __shared__ short Bs[128][68];
    f32x4 acc[4][4] = {};

    for (int ks = 0; ks < 5; ++ks) {
        __syncthreads();
        for (int u = 0; u < 4; ++u) {
            int idx = u * 256 + tid;          // 0..1023
            int rr = idx >> 3, c8 = idx & 7;
            *reinterpret_cast<bf16x8*>(&As[rr][c8 * 8]) =
                *reinterpret_cast<const bf16x8*>(Xb + (mt0 + rr) * 320 + ks * 64 + c8 * 8);
            *reinterpret_cast<bf16x8*>(&Bs[rr][c8 * 8]) =
                *reinterpret_cast<const bf16x8*>(WvT + (size_t)(nt0 + rr) * 320 + ks * 64 + c8 * 8);
        }
        __syncthreads();
        #pragma unroll
        for (int kk = 0; kk < 2; ++kk) {
            bf16x8 af[4], bfv[4];
            #pragma unroll
            for (int f = 0; f < 4; ++f)
                af[f] = *reinterpret_cast<const bf16x8*>(&As[wm * 64 + f * 16 + lr][kk * 32 + lg * 8]);
            #pragma unroll
            for (int f = 0; f < 4; ++f)
                bfv[f] = *reinterpret_cast<const bf16x8*>(&Bs[wn * 64 + f * 16 + lr][kk * 32 + lg * 8]);
            #pragma unroll
            for (int i = 0; i < 4; ++i)
                #pragma unroll
                for (int j = 0; j < 4; ++j)
                    acc[i][j] = __builtin_amdgcn_mfma_f32_16x16x32_bf16(af[i], bfv[j], acc[i][j], 0, 0, 0);
        }
    }
    #pragma unroll
    for (int i = 0; i < 4; ++i)
        #pragma unroll
        for (int j = 0; j < 4; ++j)
            #pragma unroll
            for (int r = 0; r < 4; ++r)
                xv[(mt0 + wm * 64 + i * 16 + lg * 4 + r) * 256 + nt0 + wn * 64 + j * 16 + lr]
                    = f2b(acc[i][j][r]);
}

// ---------------------------------------------------------------------------
// qattn v5: v4 + (a) 2-deep staging register pipeline (write of chunk ks
// waits loads issued at ks-2 -> ~2 K-steps of latency cover), (b) scores-phase
// X fragments bulk-prefetched into registers under the qs-write window.
// ---------------------------------------------------------------------------
#define QGEMM_COMPUTE                                                                        \
    {                                                                                        \
        bf16x8 af[5], bfr[5];                                                                \
        _Pragma("unroll")                                                                    \
        for (int i = 0; i < 5; ++i)                                                          \
            af[i] = *reinterpret_cast<const bf16x8*>(&Asg[wm * 80 + i * 16 + lr][lg * 8]);   \
        _Pragma("unroll")                                                                    \
        for (int j = 0; j < 5; ++j)                                                          \
            bfr[j] = *reinterpret_cast<const bf16x8*>(&Bsg[wn * 80 + j * 16 + lr][lg * 8]);  \
        _Pragma("unroll")                                                                    \
        for (int i = 0; i < 5; ++i)                                                          \
            _Pragma("unroll")                                                                \
            for (int j = 0; j < 5; ++j)                                                      \
                acc[i][j] = __builtin_amdgcn_mfma_f32_16x16x32_bf16(af[i], bfr[j], acc[i][j], 0, 0, 0); \
    }

__global__ __launch_bounds__(512, 2) void qattn(
    const short* __restrict__ Xb,    // [32000][320]
    const short* __restrict__ WqT,   // [16][320][320]
    const short* __restrict__ xv,    // [32000][256]
    float*       __restrict__ out1)  // [32000][256]
{
    const int g = blockIdx.x;        // 160-row chunk (8 bs)
    const int n = blockIdx.y;        // head
    const int tid = threadIdx.x, wave = tid >> 6, lane = tid & 63;
    const int lr = lane & 15, lg = lane >> 4;
    const int wm = wave >> 2, wn = wave & 3;
    const size_t row0 = (size_t)g * 160;

    __shared__ short qs[160][328];   // q tile (164dw stride, bank-uniform)
    __shared__ short Asg[160][36];   // X K-chunk (18dw stride)
    __shared__ short Bsg[320][36];   // WqT K-chunk
    __shared__ short atw[8][32][34]; // per-bs attn (pads zero)

    // zero atw
    for (int i = tid; i < 4352; i += 512) reinterpret_cast<int*>(atw)[i] = 0;

    const short* wh = WqT + (size_t)n * 320 * 320;

    // staging roles: threads 0..159 -> A row tid; 160..479 -> B row tid-160
    const bool isA = tid < 160;
    const bool stg = tid < 480;
    const short* gsrc = isA ? (Xb + (row0 + tid) * 320)
                            : (wh + (size_t)(stg ? tid - 160 : 0) * 320);
    short* ldst = isA ? &Asg[tid][0] : &Bsg[stg ? tid - 160 : 0][0];

    // 2-deep staging prefetch: set A = chunk 0, set B = chunk 1
    bf16x8 sA0, sA1, sA2, sA3, sB0, sB1, sB2, sB3;
    if (stg) {
        sA0 = *reinterpret_cast<const bf16x8*>(gsrc);
        sA1 = *reinterpret_cast<const bf16x8*>(gsrc + 8);
        sA2 = *reinterpret_cast<const bf16x8*>(gsrc + 16);
        sA3 = *reinterpret_cast<const bf16x8*>(gsrc + 24);
        sB0 = *reinterpret_cast<const bf16x8*>(gsrc + 32);
        sB1 = *reinterpret_cast<const bf16x8*>(gsrc + 40);
        sB2 = *reinterpret_cast<const bf16x8*>(gsrc + 48);
        sB3 = *reinterpret_cast<const bf16x8*>(gsrc + 56);
    }

    // prefetch xv B-frag for v-phase (wave = bs)
    bf16x8 bv;
    {
        const int b = wave;
        #pragma unroll
        for (int j = 0; j < 8; ++j) {
            int m = lg * 8 + j; if (m > 19) m = 19;   // attn cols >=20 are zero
            bv[j] = xv[(row0 + b * 20 + m) * 256 + n * 16 + lr];
        }
    }

    // ---- q-GEMM K-loop, unrolled x2 over the 2 staging register sets ----
    f32x4 acc[5][5] = {};
    #pragma unroll
    for (int kp = 0; kp < 5; ++kp) {
        // even step: chunk 2*kp from set A
        __syncthreads();
        if (stg) {
            *reinterpret_cast<bf16x8*>(ldst)      = sA0;
            *reinterpret_cast<bf16x8*>(ldst + 8)  = sA1;
            *reinterpret_cast<bf16x8*>(ldst + 16) = sA2;
            *reinterpret_cast<bf16x8*>(ldst + 24) = sA3;
        }
        __syncthreads();
        if (kp < 4 && stg) {                   // reload set A with chunk 2*kp+2
            const short* s = gsrc + (kp * 2 + 2) * 32;
            sA0 = *reinterpret_cast<const bf16x8*>(s);
            sA1 = *reinterpret_cast<const bf16x8*>(s + 8);
            sA2 = *reinterpret_cast<const bf16x8*>(s + 16);
            sA3 = *reinterpret_cast<const bf16x8*>(s + 24);
        }
        QGEMM_COMPUTE;
        // odd step: chunk 2*kp+1 from set B
        __syncthreads();
        if (stg) {
            *reinterpret_cast<bf16x8*>(ldst)      = sB0;
            *reinterpret_cast<bf16x8*>(ldst + 8)  = sB1;
            *reinterpret_cast<bf16x8*>(ldst + 16) = sB2;
            *reinterpret_cast<bf16x8*>(ldst + 24) = sB3;
        }
        __syncthreads();
        if (kp < 4 && stg) {                   // reload set B with chunk 2*kp+3
            const short* s = gsrc + (kp * 2 + 3) * 32;
            sB0 = *reinterpret_cast<const bf16x8*>(s);
            sB1 = *reinterpret_cast<const bf16x8*>(s + 8);
            sB2 = *reinterpret_cast<const bf16x8*>(s + 16);
            sB3 = *reinterpret_cast<const bf16x8*>(s + 24);
        }
        QGEMM_COMPUTE;
    }

    // ---- bulk-prefetch scores-phase X fragments (fly under qs write) ----
    const int b = wave;
    const int rA0 = b * 20 + lr;
    int rA1 = b * 20 + 16 + lr; if (rA1 > 159) rA1 = 159;
    const size_t rB0g = row0 + b * 20 + lr;
    size_t rB1g = row0 + b * 20 + 16 + lr; if (rB1g > 31999) rB1g = 31999;

    bf16x8 xpre0[10], xpre1[10];
    #pragma unroll
    for (int ks = 0; ks < 10; ++ks) {
        xpre0[ks] = *reinterpret_cast<const bf16x8*>(Xb + rB0g * 320 + ks * 32 + lg * 8);
        xpre1[ks] = *reinterpret_cast<const bf16x8*>(Xb + rB1g * 320 + ks * 32 + lg * 8);
    }

    // ---- acc -> qs (bf16) ----
    #pragma unroll
    for (int i = 0; i < 5; ++i)
        #pragma unroll
        for (int j = 0; j < 5; ++j)
            #pragma unroll
            for (int r = 0; r < 4; ++r)
                qs[wm * 80 + i * 16 + lg * 4 + r][wn * 80 + j * 16 + lr] = f2b(acc[i][j][r]);
    __syncthreads();

    // ---- scores + in-register softmax: wave = bs ----
    {
        f32x4 s[2][2] = {};
        #pragma unroll
        for (int ks = 0; ks < 10; ++ks) {
            const int kc = ks * 32 + lg * 8;
            bf16x8 a0 = *reinterpret_cast<const bf16x8*>(&qs[rA0][kc]);
            bf16x8 a1 = *reinterpret_cast<const bf16x8*>(&qs[rA1][kc]);
            s[0][0] = __builtin_amdgcn_mfma_f32_16x16x32_bf16(a0, xpre0[ks], s[0][0], 0, 0, 0);
            s[0][1] = __builtin_amdgcn_mfma_f32_16x16x32_bf16(a0, xpre1[ks], s[0][1], 0, 0, 0);
            s[1][0] = __builtin_amdgcn_mfma_f32_16x16x32_bf16(a1, xpre0[ks], s[1][0], 0, 0, 0);
            s[1][1] = __builtin_amdgcn_mfma_f32_16x16x32_bf16(a1, xpre1[ks], s[1][1], 0, 0, 0);
        }

        const float scl = 0.057735026918962584f;  // 1/sqrt(300)
        #pragma unroll
        for (int mts = 0; mts < 2; ++mts) {
            #pragma unroll
            for (int r = 0; r < 4; ++r) {
                float v0 = s[mts][0][r] * scl;
                float v1 = s[mts][1][r] * scl;
                float mx = (lr < 4) ? fmaxf(v0, v1) : v0;
                mx = fmaxf(mx, __shfl_xor(mx, 1));
                mx = fmaxf(mx, __shfl_xor(mx, 2));
                mx = fmaxf(mx, __shfl_xor(mx, 4));
                mx = fmaxf(mx, __shfl_xor(mx, 8));
                float e0 = __expf(v0 - mx);
                float e1 = (lr < 4) ? __expf(v1 - mx) : 0.f;
                float sm = e0 + e1;
                sm += __shfl_xor(sm, 1);
                sm += __shfl_xor(sm, 2);
                sm += __shfl_xor(sm, 4);
                sm += __shfl_xor(sm, 8);
                const float inv = 1.f / sm;
                const int row = mts * 16 + lg * 4 + r;
                if (row < LL) {
                    atw[b][row][lr]      = f2b(e0 * inv);
                    atw[b][row][16 + lr] = f2b(e1 * inv);   // lr>=4 writes 0
                }
            }
        }
    }
    __syncthreads();

    // ---- v = attn * xv : wave = bs, both mt tiles ----
    {
        bf16x8 va0 = *reinterpret_cast<const bf16x8*>(&atw[b][lr][lg * 8]);
        bf16x8 va1 = *reinterpret_cast<const bf16x8*>(&atw[b][16 + lr][lg * 8]);
        f32x4 z = {0.f, 0.f, 0.f, 0.f};
        f32x4 v0 = __builtin_amdgcn_mfma_f32_16x16x32_bf16(va0, bv, z, 0, 0, 0);
        f32x4 v1 = __builtin_amdgcn_mfma_f32_16x16x32_bf16(va1, bv, z, 0, 0, 0);
        #pragma unroll
        for (int r = 0; r < 4; ++r) {
            const int rowl = lg * 4 + r;
            out1[(row0 + b * 20 + rowl) * 256 + n * 16 + lr] = v0[r];
            const int rowl1 = 16 + lg * 4 + r;
            if (rowl1 < LL)
                out1[(row0 + b * 20 + rowl1) * 256 + n * 16 + lr] = v1[r];
        }
    }
}

// ---------------------------------------------------------------------------
// Additive attention pooling per bs, MFMA add_key. grid 1600, block 256.
// ---------------------------------------------------------------------------
__global__ __launch_bounds__(256) void nrms_pool_mfma(
    const float* __restrict__ out1,
    const short* __restrict__ kwb,    // [208][256] bf16
    const float* __restrict__ keyB,   // [200]
    const float* __restrict__ query,  // [200]
    float*       __restrict__ out2)   // [NBS][256]
{
    const int bs   = blockIdx.x;
    const int tid  = threadIdx.x;
    const int wave = tid >> 6;
    const int lane = tid & 63;
    const int lr   = lane & 15;
    const int lg   = lane >> 4;

    __shared__ float mh[LL][257];
    __shared__ short mhb[32][264];   // 132 dw == 4 mod 32
    __shared__ float s2p[32];

    for (int i = tid; i < 12 * 128; i += 256) {
        const int r = 20 + i / 128, c = (i % 128) * 2;
        *reinterpret_cast<int*>(&mhb[r][c]) = 0;
    }
    if (tid < 32) s2p[tid] = 0.f;

    for (int idx = tid; idx < LL * 64; idx += 256) {
        const int l = idx >> 6, h4 = (idx & 63) * 4;
        const float4 v = *reinterpret_cast<const float4*>(out1 + ((size_t)bs * LL + l) * HID + h4);
        mh[l][h4] = v.x; mh[l][h4 + 1] = v.y; mh[l][h4 + 2] = v.z; mh[l][h4 + 3] = v.w;
        mhb[l][h4] = f2b(v.x); mhb[l][h4 + 1] = f2b(v.y);
        mhb[l][h4 + 2] = f2b(v.z); mhb[l][h4 + 3] = f2b(v.w);
    }
    __syncthreads();

    for (int t = wave; t < 26; t += 4) {
        const int mt = t & 1, nt = t >> 1;
        f32x4 acc = {0.f, 0.f, 0.f, 0.f};
        const short* ap = &mhb[mt * 16 + lr][lg * 8];
        const short* bp = kwb + (nt * 16 + lr) * 256 + lg * 8;
        #pragma unroll
        for (int k = 0; k < 8; ++k) {
            bf16x8 a = *reinterpret_cast<const bf16x8*>(ap + k * 32);
            bf16x8 b = *reinterpret_cast<const bf16x8*>(bp + k * 32);
            acc = __builtin_amdgcn_mfma_f32_16x16x32_bf16(a, b, acc, 0, 0, 0);
        }
        const int d = nt * 16 + lr;
        const float qd = (d < QD) ? query[d] : 0.f;
        const float kb = (d < QD) ? keyB[d] : 0.f;
        float vals[4];
        #pragma unroll
        for (int r = 0; r < 4; ++r) vals[r] = qd * ftanh(acc[r] + kb);
        #pragma unroll
        for (int off = 1; off < 16; off <<= 1) {
            #pragma unroll
            for (int r = 0; r < 4; ++r) vals[r] += __shfl_xor(vals[r], off);
        }
        if (lr == 0) {
            #pragma unroll
            for (int r = 0; r < 4; ++r)
                atomicAdd(&s2p[mt * 16 + lg * 4 + r], vals[r]);
        }
    }
    __syncthreads();

    if (tid == 0) {
        float mx = -1e30f;
        #pragma unroll
        for (int l = 0; l < LL; ++l) mx = fmaxf(mx, s2p[l] * 0.07071067811865475f);
        float sum = 0.f;
        float e[LL];
        #pragma unroll
        for (int l = 0; l < LL; ++l) { e[l] = __expf(s2p[l] * 0.07071067811865475f - mx); sum += e[l]; }
        const float inv = 1.f / sum;
        #pragma unroll
        for (int l = 0; l < LL; ++l) s2p[l] = e[l] * inv;
    }
    __syncthreads();

    {
        const int h = tid;
        float acc = 0.f;
        #pragma unroll
        for (int l = 0; l < LL; ++l) acc = fmaf(s2p[l], mh[l][h], acc);
        out2[(size_t)bs * HID + h] = acc;
    }
}

// ===========================================================================
// FALLBACK PATH (round-3, needs only 3.4 MB ws) — used if ws_size too small
// ===========================================================================

#define XP 330
#define TP 42
#define AP 34

__global__ __launch_bounds__(1024) void transpose_qw(
    const float* __restrict__ qW, short* __restrict__ wqt)
{
    __shared__ float t[32][33];
    const int n = blockIdx.z;
    const int e0 = blockIdx.x * 32, f0 = blockIdx.y * 32;
    const int tx = threadIdx.x, ty = threadIdx.y;
    const int e = e0 + ty, f = f0 + tx;
    t[ty][tx] = (e < EE && f < EE) ? qW[(size_t)n * EE * EE + e * EE + f] : 0.f;
    __syncthreads();
    const int fo = f0 + ty, eo = e0 + tx;
    if (fo < 304)
        wqt[(size_t)n * 304 * 320 + fo * 320 + eo] = f2b(t[tx][ty]);
}

__global__ void conv_vw(const float* __restrict__ vW, short* __restrict__ wvt) {
    int idx = blockIdx.x * 256 + threadIdx.x;
    if (idx >= NH * VD * 320) return;
    int e = idx % 320;
    int v = (idx / 320) % VD;
    int n = idx / (320 * VD);
    wvt[idx] = (e < EE) ? f2b(vW[(size_t)n * EE * VD + e * VD + v]) : (short)0;
}

__global__ __launch_bounds__(512) void nrms_attn_mfma(
    const int*   __restrict__ news,
    const float* __restrict__ emb,
    const short* __restrict__ wqt,
    const float* __restrict__ qB,
    const short* __restrict__ wvt,
    const float* __restrict__ vB,
    float*       __restrict__ out1)
{
    const int bs   = blockIdx.x;
    const int tid  = threadIdx.x;
    const int wave = tid >> 6;
    const int lane = tid & 63;
    const int lr   = lane & 15;
    const int lg   = lane >> 4;

    __shared__ short xs[32][XP];
    __shared__ short xT[320][TP];
    __shared__ short qs[32][XP];
    __shared__ float sc[32][33];
    __shared__ short at[32][AP];

    {
        int* z = (int*)&xs[0][0];
        for (int i = tid; i < 32 * XP / 2; i += 512) z[i] = 0;
        z = (int*)&qs[0][0];
        for (int i = tid; i < 32 * XP / 2; i += 512) z[i] = 0;
        z = (int*)&xT[0][0];
        for (int i = tid; i < 320 * TP / 2; i += 512) z[i] = 0;
    }
    __syncthreads();

    for (int idx = tid; idx < LL * 75; idx += 512) {
        const int l = idx / 75, e4 = (idx % 75) * 4;
        const int row = news[bs * LL + l];
        const float4 v = *reinterpret_cast<const float4*>(emb + (size_t)row * EE + e4);
        const short b0 = f2b(v.x), b1 = f2b(v.y), b2 = f2b(v.z), b3 = f2b(v.w);
        xs[l][e4] = b0; xs[l][e4 + 1] = b1; xs[l][e4 + 2] = b2; xs[l][e4 + 3] = b3;
        xT[e4][l] = b0; xT[e4 + 1][l] = b1; xT[e4 + 2][l] = b2; xT[e4 + 3][l] = b3;
    }
    __syncthreads();

    for (int n = 0; n < NH; ++n) {
        const short* wq = wqt + (size_t)n * 304 * 320;

        for (int p = wave; p < 19; p += 8) {
            f32x4 acc0 = {0.f, 0.f, 0.f, 0.f};
            f32x4 acc1 = {0.f, 0.f, 0.f, 0.f};
            const short* a0p = &xs[lr][lg * 8];
            const short* a1p = &xs[16 + lr][lg * 8];
            const short* bp  = wq + (p * 16 + lr) * 320 + lg * 8;
            #pragma unroll
            for (int k = 0; k < 10; ++k) {
                bf16x8 b  = *reinterpret_cast<const bf16x8*>(bp + k * 32);
                bf16x8 a0 = *reinterpret_cast<const bf16x8*>(a0p + k * 32);
                bf16x8 a1 = *reinterpret_cast<const bf16x8*>(a1p + k * 32);
                acc0 = __builtin_amdgcn_mfma_f32_16x16x32_bf16(a0, b, acc0, 0, 0, 0);
                acc1 = __builtin_amdgcn_mfma_f32_16x16x32_bf16(a1, b, acc1, 0, 0, 0);
            }
            const int col = p * 16 + lr;
            const float bias = (col < EE) ? qB[n * EE + col] : 0.f;
            #pragma unroll
            for (int r = 0; r < 4; ++r) {
                qs[lg * 4 + r][col]      = f2b(acc0[r] + bias);
                qs[16 + lg * 4 + r][col] = f2b(acc1[r] + bias);
            }
        }
        __syncthreads();

        if (wave < 4) {
            const int mt = wave & 1, nt = wave >> 1;
            f32x4 acc = {0.f, 0.f, 0.f, 0.f};
            const short* ap = &qs[mt * 16 + lr][lg * 8];
            const short* bp = &xs[nt * 16 + lr][lg * 8];
            #pragma unroll
            for (int k = 0; k < 10; ++k) {
                bf16x8 a = *reinterpret_cast<const bf16x8*>(ap + k * 32);
                bf16x8 b = *reinterpret_cast<const bf16x8*>(bp + k * 32);
                acc = __builtin_amdgcn_mfma_f32_16x16x32_bf16(a, b, acc, 0, 0, 0);
            }
            #pragma unroll
            for (int r = 0; r < 4; ++r)
                sc[mt * 16 + lg * 4 + r][nt * 16 + lr] = acc[r] * 0.057735026918962584f;
        }
        __syncthreads();

        if (tid < LL) {
            float mx = -1e30f;
            #pragma unroll
            for (int m = 0; m < LL; ++m) mx = fmaxf(mx, sc[tid][m]);
            float ev[LL], sum = 0.f;
            #pragma unroll
            for (int m = 0; m < LL; ++m) { ev[m] = __expf(sc[tid][m] - mx); sum += ev[m]; }
            const float inv = 1.f / sum;
            #pragma unroll
            for (int m = 0; m < LL; ++m) at[tid][m] = f2b(ev[m] * inv);
            #pragma unroll
            for (int m = LL; m < 32; ++m) at[tid][m] = 0;
        } else if (tid < 32) {
            int* zr = (int*)&at[tid][0];
            #pragma unroll
            for (int m = 0; m < 16; ++m) zr[m] = 0;
        }
        __syncthreads();

        for (int p = wave; p < 19; p += 8) {
            bf16x8 b  = *reinterpret_cast<const bf16x8*>(&xT[p * 16 + lr][lg * 8]);
            bf16x8 a0 = *reinterpret_cast<const bf16x8*>(&at[lr][lg * 8]);
            bf16x8 a1 = *reinterpret_cast<const bf16x8*>(&at[16 + lr][lg * 8]);
            f32x4 z = {0.f, 0.f, 0.f, 0.f};
            f32x4 c0 = __builtin_amdgcn_mfma_f32_16x16x32_bf16(a0, b, z, 0, 0, 0);
            f32x4 c1 = __builtin_amdgcn_mfma_f32_16x16x32_bf16(a1, b, z, 0, 0, 0);
            const int col = p * 16 + lr;
            #pragma unroll
            for (int r = 0; r < 4; ++r) {
                qs[lg * 4 + r][col]      = f2b(c0[r]);
                qs[16 + lg * 4 + r][col] = f2b(c1[r]);
            }
        }
        __syncthreads();

        if (wave < 2) {
            const int mt = wave;
            f32x4 acc = {0.f, 0.f, 0.f, 0.f};
            const short* ap = &qs[mt * 16 + lr][lg * 8];
            const short* bp = wvt + (size_t)n * VD * 320 + lr * 320 + lg * 8;
            #pragma unroll
            for (int k = 0; k < 10; ++k) {
                bf16x8 a = *reinterpret_cast<const bf16x8*>(ap + k * 32);
                bf16x8 b = *reinterpret_cast<const bf16x8*>(bp + k * 32);
                acc = __builtin_amdgcn_mfma_f32_16x16x32_bf16(a, b, acc, 0, 0, 0);
            }
            #pragma unroll
            for (int r = 0; r < 4; ++r) {
                const int row = mt * 16 + lg * 4 + r;
                if (row < LL)
                    out1[((size_t)bs * LL + row) * HID + n * VD + lr] = acc[r] + vB[n * VD + lr];
            }
        }
        __syncthreads();
    }
}

// ===========================================================================

extern "C" void kernel_launch(void* const* d_in, const int* in_sizes, int n_in,
                              void* d_out, int out_size, void* d_ws, size_t ws_size,
                              hipStream_t stream) {
    const int*   news  = (const int*)d_in[0];
    const float* emb   = (const float*)d_in[1];
    const float* qW    = (const float*)d_in[2];
    const float* qB    = (const float*)d_in[3];
    const float* vW    = (const float*)d_in[4];
    const float* vB    = (const float*)d_in[5];
    const float* keyW  = (const float*)d_in[6];
    const float* keyB  = (const float*)d_in[7];
    const float* query = (const float*)d_in[8];

    float* out1 = (float*)d_out;            // news_embedding: 8192000 floats
    float* out2 = out1 + 8192000;           // news_repr: 409600 floats

    const size_t NEED = ((size_t)10240000 + 1638400 + 81920 + 8192000 + 53248) * 2;

    if (ws_size >= NEED) {
        short* Xb  = (short*)d_ws;                  // 32000*320
        short* WqT = Xb + 10240000;                 // 16*320*320
        short* WvT = WqT + 1638400;                 // 256*320
        short* xv  = WvT + 81920;                   // 32000*256
        short* kwb = xv + 8192000;                  // 208*256

        hipLaunchKernelGGL(build_xb, dim3(10000), dim3(256), 0, stream, news, emb, Xb);
        hipLaunchKernelGGL(build_wqt, dim3(10, 10, 16), dim3(32, 32), 0, stream, qW, qB, WqT);
        hipLaunchKernelGGL(build_wvt, dim3(320), dim3(256), 0, stream, vW, vB, WvT);
        hipLaunchKernelGGL(conv_kw, dim3(208), dim3(256), 0, stream, keyW, kwb);
        hipLaunchKernelGGL(gemm_xv, dim3(2, 250), dim3(256), 0, stream, Xb, WvT, xv);
        hipLaunchKernelGGL(qattn, dim3(200, 16), dim3(512), 0, stream, Xb, WqT, xv, out1);
        hipLaunchKernelGGL(nrms_pool_mfma, dim3(NBS), dim3(256), 0, stream,
                           out1, kwb, keyB, query, out2);
    } else {
        short* wqt = (short*)d_ws;
        short* wvt = wqt + (size_t)NH * 304 * 320;
        short* kwb = wvt + (size_t)NH * VD * 320;

        hipLaunchKernelGGL(transpose_qw, dim3(10, 10, 16), dim3(32, 32), 0, stream, qW, wqt);
        hipLaunchKernelGGL(conv_vw, dim3(320), dim3(256), 0, stream, vW, wvt);
        hipLaunchKernelGGL(conv_kw, dim3(208), dim3(256), 0, stream, keyW, kwb);
        hipLaunchKernelGGL(nrms_attn_mfma, dim3(NBS), dim3(512), 0, stream,
                           news, emb, wqt, qB, wvt, vB, out1);
        hipLaunchKernelGGL(nrms_pool_mfma, dim3(NBS), dim3(256), 0, stream,
                           out1, kwb, keyB, query, out2);
    }
}